// Round 7
// baseline (84.503 us; speedup 1.0000x reference)
//
#include <hip/hip_runtime.h>
#include <math.h>

// Per-row VQ: sorted codebook + branchless binary search + PREFERENCE-ORDERED
// boundary pairs.
//   x: [4096, 2048] fp32, values: [4096, 16] fp32
//   out[r][c] = values[r][argmin_v fl(fl(x-v)^2)], first-index tie-break.
//
// Exactness (absmax must be 0):
//  - fl(t^2) monotone in |t| => argmin attained at a sorted neighbor of x
//    (non-neighbor ties differ in VALUE by < ~3e-7, far below threshold;
//    scored absmax 0.0 in R6 with the same argument).
//  - pair[b] = (P,Q) with P = tie-preferred (lower min-original-index of its
//    equal-value run, numpy argmin-first). o = (dQ < dP) ? Q : P -- strict <
//    sends exact rounded-square ties to P. Bit-exact vs numpy.
//  - boundary 15 pairs v[15] with +inf: dQ=inf never wins strict <.
//  - x below range -> pos=0, pair (sv0,sv1) contains the true nearest.
//
// Lessons kept: R4 nontemporal hints regressed (-5%) -- plain loads/stores.
// Issue model (measured 0.117 us per VALU issue/element): ~25 -> ~17.

#define N_ROWS 4096
#define N_COLS 2048
#define N_VALS 16

typedef float f32x2 __attribute__((ext_vector_type(2)));
typedef float f32x4 __attribute__((ext_vector_type(4)));

__global__ __launch_bounds__(256) void vq_rowcodebook_kernel(
    const float* __restrict__ x,
    const float* __restrict__ values,
    float* __restrict__ out)
{
    const int row = blockIdx.x;
    const float* vr = values + (size_t)row * N_VALS;
    const int tid = threadIdx.x;

    __shared__ float sv[N_VALS + 1];    // sorted values, +inf sentinel
    __shared__ int   smin[N_VALS + 1];  // min ORIGINAL idx of equal-value run
    __shared__ f32x2 pair[N_VALS];      // per-boundary (P,Q), P = tie-preferred

    if (tid < N_VALS) {
        const float vi = vr[tid];
        int rank = 0, mi = tid;
#pragma unroll
        for (int j = 0; j < N_VALS; ++j) {
            const float vj = vr[j];
            rank += (vj < vi || (vj == vi && j < tid)) ? 1 : 0;  // stable rank
            mi    = (vj == vi && j < mi) ? j : mi;               // run min idx
        }
        sv[rank] = vi; smin[rank] = mi;
        if (tid == 0) { sv[N_VALS] = INFINITY; smin[N_VALS] = 0x7fffffff; }
    }
    __syncthreads();
    if (tid < N_VALS) {
        const float L = sv[tid], R = sv[tid + 1];
        const bool prefL = smin[tid] < smin[tid + 1];
        f32x2 pq; pq.x = prefL ? L : R; pq.y = prefL ? R : L;
        pair[tid] = pq;
    }
    __syncthreads();

    // Hoisted pivots (loop-invariant LDS reads).
    const float p4 = sv[4], p8 = sv[8], p12 = sv[12];
    const char* svb = (const char*)sv;
    const char* prb = (const char*)pair;

    const f32x4* xr   = (const f32x4*)(x   + (size_t)row * N_COLS);
    f32x4*       outr = (f32x4*)      (out + (size_t)row * N_COLS);

    // 2048 cols = 512 float4; 256 threads -> 2 iterations, fully coalesced.
#pragma unroll
    for (int it = 0; it < 2; ++it) {
        const int j = tid + it * 256;
        const f32x4 xv = xr[j];

        f32x4 o;
#pragma unroll
        for (int e = 0; e < 4; ++e) {
            const float xe = xv[e];

            // Branchless lower-bound: pb/4 = largest t in [0,15] with
            // sv[t] <= xe (0 if none). Steps 8,4 folded into registers.
            const bool b1 = (p8 <= xe);
            int pb = b1 ? 32 : 0;
            const float pv2 = b1 ? p12 : p4;
            pb += (pv2 <= xe) ? 16 : 0;
            pb += (*(const float*)(svb + pb + 8) <= xe) ? 8 : 0;   // sv[pos+2]
            pb += (*(const float*)(svb + pb + 4) <= xe) ? 4 : 0;   // sv[pos+1]

            const f32x2 pq = *(const f32x2*)(prb + (pb << 1));     // (P,Q)

            f32x2 xe2; xe2.x = xe; xe2.y = xe;
            const f32x2 t = xe2 - pq;      // v_pk_add_f32 (neg mod)
            const f32x2 d = t * t;         // v_pk_mul_f32
            // strict <: exact tie -> P (tie-preferred), numpy-first semantics.
            o[e] = (d.y < d.x) ? pq.y : pq.x;
        }
        outr[j] = o;
    }
}

extern "C" void kernel_launch(void* const* d_in, const int* in_sizes, int n_in,
                              void* d_out, int out_size, void* d_ws, size_t ws_size,
                              hipStream_t stream) {
    const float* x      = (const float*)d_in[0];
    const float* values = (const float*)d_in[1];
    float* out          = (float*)d_out;

    vq_rowcodebook_kernel<<<N_ROWS, 256, 0, stream>>>(x, values, out);
}

// Round 8
// 83.686 us; speedup vs baseline: 1.0098x; 1.0098x over previous
//
#include <hip/hip_runtime.h>
#include <math.h>

// Per-row VQ: sorted codebook + branchless binary search + preference-ordered
// boundary pairs, SCALAR epilogue (R7's packed-f32x2 epilogue regressed —
// suspected v_pk scalarization/shuffle overhead; R4's nontemporal hints also
// regressed. Both reverted.)
//
//   x: [4096, 2048] fp32, values: [4096, 16] fp32
//   out[r][c] = values[r][argmin_v fl(fl(x-v)^2)], first-index tie-break.
//
// Exactness (absmax 0.0 in R6/R7 with this argument):
//  - fl(t^2) monotone in |t| => argmin attained at a sorted neighbor of x.
//  - pair[b] = (P,Q), P = tie-preferred (lower min-original-index of its
//    equal-value run). o = (dQ < dP) ? Q : P; strict < sends exact
//    rounded-square ties to P = numpy argmin-first semantics.
//  - boundary 15 pairs v[15] with +inf: dQ=inf never wins strict <.
//  - x below range -> pos=0, candidates (sv0,sv1) contain the true nearest.

#define N_ROWS 4096
#define N_COLS 2048
#define N_VALS 16

typedef float f32x2 __attribute__((ext_vector_type(2)));
typedef float f32x4 __attribute__((ext_vector_type(4)));

__global__ __launch_bounds__(256) void vq_rowcodebook_kernel(
    const float* __restrict__ x,
    const float* __restrict__ values,
    float* __restrict__ out)
{
    const int row = blockIdx.x;
    const float* vr = values + (size_t)row * N_VALS;
    const int tid = threadIdx.x;

    __shared__ float sv[N_VALS + 1];    // sorted values, +inf sentinel
    __shared__ int   smin[N_VALS + 1];  // min ORIGINAL idx of equal-value run
    __shared__ f32x2 pair[N_VALS];      // per-boundary (P,Q), P = tie-preferred

    if (tid < N_VALS) {
        const float vi = vr[tid];
        int rank = 0, mi = tid;
#pragma unroll
        for (int j = 0; j < N_VALS; ++j) {
            const float vj = vr[j];
            rank += (vj < vi || (vj == vi && j < tid)) ? 1 : 0;  // stable rank
            mi    = (vj == vi && j < mi) ? j : mi;               // run min idx
        }
        sv[rank] = vi; smin[rank] = mi;
        if (tid == 0) { sv[N_VALS] = INFINITY; smin[N_VALS] = 0x7fffffff; }
    }
    __syncthreads();
    if (tid < N_VALS) {
        const float L = sv[tid], R = sv[tid + 1];
        const bool prefL = smin[tid] < smin[tid + 1];
        f32x2 pq; pq.x = prefL ? L : R; pq.y = prefL ? R : L;
        pair[tid] = pq;
    }
    __syncthreads();

    // Hoisted pivots (loop-invariant LDS reads).
    const float p4 = sv[4], p8 = sv[8], p12 = sv[12];
    const char* svb = (const char*)sv;
    const char* prb = (const char*)pair;

    const f32x4* xr   = (const f32x4*)(x   + (size_t)row * N_COLS);
    f32x4*       outr = (f32x4*)      (out + (size_t)row * N_COLS);

    // Both 16B loads issued up front: cross-iteration HBM latency overlap.
    const int j0 = tid, j1 = tid + 256;
    const f32x4 xv0 = xr[j0];
    const f32x4 xv1 = xr[j1];

    f32x4 xs[2] = {xv0, xv1};
    f32x4 os[2];
#pragma unroll
    for (int it = 0; it < 2; ++it) {
#pragma unroll
        for (int e = 0; e < 4; ++e) {
            const float xe = xs[it][e];

            // Branchless lower-bound: pb/4 = largest t in [0,15] with
            // sv[t] <= xe (0 if none). First two levels in registers.
            const bool b1 = (p8 <= xe);
            int pb = b1 ? 32 : 0;
            const float pv2 = b1 ? p12 : p4;
            pb += (pv2 <= xe) ? 16 : 0;
            pb += (*(const float*)(svb + pb + 8) <= xe) ? 8 : 0;   // sv[pos+2]
            pb += (*(const float*)(svb + pb + 4) <= xe) ? 4 : 0;   // sv[pos+1]

            const f32x2 pq = *(const f32x2*)(prb + (pb << 1));     // (P,Q)

            // Scalar epilogue: deterministic codegen, 6 VALU.
            const float tP = xe - pq.x;
            const float tQ = xe - pq.y;
            const float dP = tP * tP;
            const float dQ = tQ * tQ;
            os[it][e] = (dQ < dP) ? pq.y : pq.x;   // strict <: tie -> P
        }
    }
    outr[j0] = os[0];
    outr[j1] = os[1];
}

extern "C" void kernel_launch(void* const* d_in, const int* in_sizes, int n_in,
                              void* d_out, int out_size, void* d_ws, size_t ws_size,
                              hipStream_t stream) {
    const float* x      = (const float*)d_in[0];
    const float* values = (const float*)d_in[1];
    float* out          = (float*)d_out;

    vq_rowcodebook_kernel<<<N_ROWS, 256, 0, stream>>>(x, values, out);
}